// Round 13
// baseline (115.327 us; speedup 1.0000x reference)
//
#include <hip/hip_runtime.h>

// Round 12: R8 config (best known: 111.6 us) + attention l via VALU row-sums
// instead of ones-MFMA (MFMA/wave-iter 40->32, VGPR -24). Final l completed
// by shfl_xor(16),(32) after the K-loop. Everything else = R8.

#define SEQ 2048
#define BATCH 4
#define NHEADS 8
#define HDIM 32
#define DIMC 256
#define SCALE_LOG2E 0.09016844005556021f  // (1/16)*log2(e)

typedef __attribute__((ext_vector_type(8))) short short8;
typedef __attribute__((ext_vector_type(4))) float f32x4;

union BF8 { unsigned u[4]; short8 s8; };

__device__ __forceinline__ unsigned pk2bf(float a, float b) {
    union { float f; unsigned u; } ua, ub;
    ua.f = a; ub.f = b;
    return __builtin_amdgcn_perm(ub.u + 0x8000u, ua.u + 0x8000u, 0x07060302u);
}
__device__ __forceinline__ short f2bf(float a) {
    union { float f; unsigned u; } x; x.f = a;
    return (short)((x.u + 0x8000u) >> 16);
}

#define NX (BATCH * SEQ * DIMC)
#define NQW (3 * DIMC * DIMC)
#define NOW (DIMC * DIMC)

__global__ __launch_bounds__(256) void cvt_bf16(const float* __restrict__ x,
                                                const float* __restrict__ wq,
                                                const float* __restrict__ wo,
                                                short* __restrict__ xb,
                                                short* __restrict__ wqb,
                                                short* __restrict__ wob) {
    int i = (blockIdx.x * 256 + threadIdx.x) * 4;
    const float* src;
    short* dst;
    int off;
    if (i < NX) { src = x; dst = xb; off = i; }
    else if (i < NX + NQW) { src = wq; dst = wqb; off = i - NX; }
    else { src = wo; dst = wob; off = i - NX - NQW; }
    float4 v = *(const float4*)&src[off];
    uint2 p;
    p.x = pk2bf(v.x, v.y);
    p.y = pk2bf(v.z, v.w);
    *(uint2*)&dst[off] = p;
}

// ---------------------------------------------------------------------------
// QKV GEMM (R7/R8): 128x64 tile, 768 blocks, software-pipelined staging.
// ---------------------------------------------------------------------------
__global__ __launch_bounds__(256) void qkv_mfma(const short* __restrict__ Xb,
                                                const short* __restrict__ Wb,
                                                const float* __restrict__ bias,
                                                short* __restrict__ Q,
                                                short* __restrict__ Kd,
                                                short* __restrict__ V) {
    __shared__ __align__(16) union SM {
        struct { short A[128][72]; short B[64][72]; } ab;
        short CQ[128][72];
        short CV[64][136];
    } sm;

    const int m0 = blockIdx.y * 128, bx = blockIdx.x;
    const int n0 = bx * 64;
    const int tid = threadIdx.x;
    const int w = tid >> 6, lane = tid & 63;
    const int m = lane & 15, g = lane >> 4;
    const int wr = w >> 1, wc = w & 1;

    const int arow = tid >> 1, acol = (tid & 1) * 32;
    const int brow = tid >> 2, bcol = (tid & 3) * 16;

    f32x4 acc[4][2] = {};

    const short* ap = Xb + (size_t)(m0 + arow) * DIMC + acol;
    const short* bp = Wb + (size_t)(n0 + brow) * DIMC + bcol;

    short8 pa[4], pb[2];
#pragma unroll
    for (int i = 0; i < 4; i++) pa[i] = *(const short8*)(ap + i * 8);
#pragma unroll
    for (int i = 0; i < 2; i++) pb[i] = *(const short8*)(bp + i * 8);

    for (int kt = 0; kt < DIMC; kt += 64) {
        __syncthreads();
#pragma unroll
        for (int i = 0; i < 4; i++) *(short8*)&sm.ab.A[arow][acol + i * 8] = pa[i];
#pragma unroll
        for (int i = 0; i < 2; i++) *(short8*)&sm.ab.B[brow][bcol + i * 8] = pb[i];
        __syncthreads();
        if (kt + 64 < DIMC) {
#pragma unroll
            for (int i = 0; i < 4; i++) pa[i] = *(const short8*)(ap + kt + 64 + i * 8);
#pragma unroll
            for (int i = 0; i < 2; i++) pb[i] = *(const short8*)(bp + kt + 64 + i * 8);
        }
#pragma unroll
        for (int kk = 0; kk < 2; kk++) {
            short8 af[4], bf[2];
#pragma unroll
            for (int mt = 0; mt < 4; mt++)
                af[mt] = *(const short8*)&sm.ab.A[wr * 64 + mt * 16 + m][kk * 32 + g * 8];
#pragma unroll
            for (int nt = 0; nt < 2; nt++)
                bf[nt] = *(const short8*)&sm.ab.B[wc * 32 + nt * 16 + m][kk * 32 + g * 8];
#pragma unroll
            for (int mt = 0; mt < 4; mt++)
#pragma unroll
                for (int nt = 0; nt < 2; nt++)
                    acc[mt][nt] = __builtin_amdgcn_mfma_f32_16x16x32_bf16(af[mt], bf[nt], acc[mt][nt], 0, 0, 0);
        }
    }

    const int which = bx >> 2;
    const int h0 = (bx & 3) * 2;
    const int bidx = blockIdx.y >> 4;
    const int ntok0 = (blockIdx.y & 15) * 128;
    float bv[2];
#pragma unroll
    for (int nt = 0; nt < 2; nt++) bv[nt] = bias[n0 + wc * 32 + nt * 16 + m];

    __syncthreads();
    if (which != 2) {
        const float qs = (which == 0) ? SCALE_LOG2E : 1.0f;
#pragma unroll
        for (int mt = 0; mt < 4; mt++)
#pragma unroll
            for (int nt = 0; nt < 2; nt++)
#pragma unroll
                for (int r = 0; r < 4; r++)
                    sm.CQ[wr * 64 + mt * 16 + g * 4 + r][wc * 32 + nt * 16 + m] =
                        f2bf((acc[mt][nt][r] + bv[nt]) * qs);
        __syncthreads();
        short* dst = (which == 0) ? Q : Kd;
        const int tok = tid >> 1, d0 = (tid & 1) * 16;
#pragma unroll
        for (int hh = 0; hh < 2; hh++) {
            size_t o = ((size_t)((bidx * NHEADS + h0 + hh) * SEQ) + ntok0 + tok) * HDIM + d0;
            *(short8*)&dst[o] = *(const short8*)&sm.CQ[tok][hh * 32 + d0];
            *(short8*)&dst[o + 8] = *(const short8*)&sm.CQ[tok][hh * 32 + d0 + 8];
        }
    } else {
#pragma unroll
        for (int mt = 0; mt < 4; mt++)
#pragma unroll
            for (int nt = 0; nt < 2; nt++) {
                uint2 p;
                p.x = pk2bf(acc[mt][nt][0] + bv[nt], acc[mt][nt][1] + bv[nt]);
                p.y = pk2bf(acc[mt][nt][2] + bv[nt], acc[mt][nt][3] + bv[nt]);
                *(uint2*)&sm.CV[wc * 32 + nt * 16 + m][wr * 64 + mt * 16 + g * 4] = p;
            }
        __syncthreads();
        const int col = tid >> 2, t0 = (tid & 3) * 32;
        const int hh = col >> 5, d = col & 31;
        size_t o = ((size_t)((bidx * NHEADS + h0 + hh) * HDIM) + d) * SEQ + ntok0 + t0;
#pragma unroll
        for (int c2 = 0; c2 < 4; c2++)
            *(short8*)&V[o + c2 * 8] = *(const short8*)&sm.CV[col][t0 + c2 * 8];
    }
}

// ---------------------------------------------------------------------------
// Attention: 128 q-rows/block, KV tile 128, k split across 4 waves (R8),
// l accumulated in VALU (8 floats) instead of ones-MFMA; completed with
// shfl_xor(16),(32) after the loop. Two-phase epilogue unchanged.
// ---------------------------------------------------------------------------
__global__ __launch_bounds__(256, 2) void attn_tile(const short* __restrict__ Q,
                                                    const short* __restrict__ K,
                                                    const short* __restrict__ V,  // [bh][d][tok]
                                                    short* __restrict__ Zb) {
    __shared__ __align__(16) union SM {
        struct { short Ks[2][128][40]; short Vs[2][32][136]; } kv;   // 37888 B
        struct { float O[4][64][36]; float L[4][64]; } ep;           // 37888 B
    } sm;

    const int bh = blockIdx.y;
    const int b = bh >> 3, h = bh & 7;
    const int q0 = blockIdx.x * 128;
    const short* qb = Q + (size_t)bh * SEQ * HDIM;
    const short* kb = K + (size_t)bh * SEQ * HDIM;
    const short* vb = V + (size_t)bh * HDIM * SEQ;
    const int tid = threadIdx.x;
    const int w = tid >> 6, lane = tid & 63;
    const int m = lane & 15, g = lane >> 4;

    short8 qfr[8];
#pragma unroll
    for (int qt = 0; qt < 8; qt++)
        qfr[qt] = *(const short8*)(qb + (size_t)(q0 + qt * 16 + m) * HDIM + g * 8);

    const int krow = tid >> 1, kcol = (tid & 1) * 16;
    const int rl = krow & 31;
    const int lrow = (krow & ~31) | (((rl >> 2) & 1) << 4) | ((rl >> 3) << 2) | (rl & 3);
    const int vrow = tid >> 3, vcol = (tid & 7) * 16;

    f32x4 o[8][2] = {};
    float lsum[8] = {};

    short8 k0a = *(const short8*)(kb + (size_t)krow * HDIM + kcol);
    short8 k0b = *(const short8*)(kb + (size_t)krow * HDIM + kcol + 8);
    short8 v0a = *(const short8*)(vb + (size_t)vrow * SEQ + vcol);
    short8 v0b = *(const short8*)(vb + (size_t)vrow * SEQ + vcol + 8);
    *(short8*)&sm.kv.Ks[0][lrow][kcol] = k0a;
    *(short8*)&sm.kv.Ks[0][lrow][kcol + 8] = k0b;
    *(short8*)&sm.kv.Vs[0][vrow][vcol] = v0a;
    *(short8*)&sm.kv.Vs[0][vrow][vcol + 8] = v0b;
    __syncthreads();

    for (int it = 0; it < SEQ / 128; ++it) {
        const int buf = it & 1;
        if (it < SEQ / 128 - 1) {
            const int kn = (it + 1) * 128;
            k0a = *(const short8*)(kb + (size_t)(kn + krow) * HDIM + kcol);
            k0b = *(const short8*)(kb + (size_t)(kn + krow) * HDIM + kcol + 8);
            v0a = *(const short8*)(vb + (size_t)vrow * SEQ + kn + vcol);
            v0b = *(const short8*)(vb + (size_t)vrow * SEQ + kn + vcol + 8);
        }

        short8 kf0 = *(const short8*)&sm.kv.Ks[buf][w * 32 + m][g * 8];
        short8 kf1 = *(const short8*)&sm.kv.Ks[buf][w * 32 + 16 + m][g * 8];
        short8 vf0 = *(const short8*)&sm.kv.Vs[buf][m][w * 32 + g * 8];
        short8 vf1 = *(const short8*)&sm.kv.Vs[buf][16 + m][w * 32 + g * 8];

#pragma unroll
        for (int qt = 0; qt < 8; qt++) {
            f32x4 z4 = {0.f, 0.f, 0.f, 0.f};
            f32x4 st0 = __builtin_amdgcn_mfma_f32_16x16x32_bf16(kf0, qfr[qt], z4, 0, 0, 0);
            f32x4 st1 = __builtin_amdgcn_mfma_f32_16x16x32_bf16(kf1, qfr[qt], z4, 0, 0, 0);
            float e0 = __builtin_amdgcn_exp2f(st0[0]);
            float e1 = __builtin_amdgcn_exp2f(st0[1]);
            float e2 = __builtin_amdgcn_exp2f(st0[2]);
            float e3 = __builtin_amdgcn_exp2f(st0[3]);
            float e4 = __builtin_amdgcn_exp2f(st1[0]);
            float e5 = __builtin_amdgcn_exp2f(st1[1]);
            float e6 = __builtin_amdgcn_exp2f(st1[2]);
            float e7 = __builtin_amdgcn_exp2f(st1[3]);
            lsum[qt] += ((e0 + e1) + (e2 + e3)) + ((e4 + e5) + (e6 + e7));
            BF8 a;
            a.u[0] = pk2bf(e0, e1);
            a.u[1] = pk2bf(e2, e3);
            a.u[2] = pk2bf(e4, e5);
            a.u[3] = pk2bf(e6, e7);
            o[qt][0] = __builtin_amdgcn_mfma_f32_16x16x32_bf16(a.s8, vf0, o[qt][0], 0, 0, 0);
            o[qt][1] = __builtin_amdgcn_mfma_f32_16x16x32_bf16(a.s8, vf1, o[qt][1], 0, 0, 0);
        }

        if (it < SEQ / 128 - 1) {
            const int nb = buf ^ 1;
            *(short8*)&sm.kv.Ks[nb][lrow][kcol] = k0a;
            *(short8*)&sm.kv.Ks[nb][lrow][kcol + 8] = k0b;
            *(short8*)&sm.kv.Vs[nb][vrow][vcol] = v0a;
            *(short8*)&sm.kv.Vs[nb][vrow][vcol + 8] = v0b;
        }
        __syncthreads();
    }

    // Complete l: lane (m,g) holds partial over its kv slice; sum across the
    // 4 g-groups (lanes m, m+16, m+32, m+48). Every lane ends with full sum.
#pragma unroll
    for (int qt = 0; qt < 8; qt++) {
        lsum[qt] += __shfl_xor(lsum[qt], 16);
        lsum[qt] += __shfl_xor(lsum[qt], 32);
    }

    // Two-phase cross-wave reduction (64 q-rows per phase).
#pragma unroll
    for (int ph = 0; ph < 2; ph++) {
        if (ph) __syncthreads();
#pragma unroll
        for (int qt = 0; qt < 4; qt++) {
            const int qq = ph * 4 + qt;
#pragma unroll
            for (int dh = 0; dh < 2; dh++)
#pragma unroll
                for (int r = 0; r < 4; r++)
                    sm.ep.O[w][qt * 16 + g * 4 + r][dh * 16 + m] = o[qq][dh][r];
            // lane (m, g=0) writes row m's l partial-total for this wave
            if (g == 0)
                sm.ep.L[w][qt * 16 + m] = lsum[qq];
        }
        __syncthreads();

        const int ql = tid >> 2, d0 = (tid & 3) * 8;
        float lt = sm.ep.L[0][ql] + sm.ep.L[1][ql] + sm.ep.L[2][ql] + sm.ep.L[3][ql];
        float inv = __builtin_amdgcn_rcpf(lt);
        float sv[8];
#pragma unroll
        for (int j = 0; j < 8; j++)
            sv[j] = sm.ep.O[0][ql][d0 + j] + sm.ep.O[1][ql][d0 + j] +
                    sm.ep.O[2][ql][d0 + j] + sm.ep.O[3][ql][d0 + j];
        BF8 pz;
#pragma unroll
        for (int j = 0; j < 4; j++)
            pz.u[j] = pk2bf(sv[2 * j] * inv, sv[2 * j + 1] * inv);
        *(short8*)&Zb[(size_t)(b * SEQ + q0 + ph * 64 + ql) * DIMC + h * HDIM + d0] = pz.s8;
    }
}

// ---------------------------------------------------------------------------
// Out GEMM (R7/R8): 64x64 tile, 512 blocks, software-pipelined staging.
// ---------------------------------------------------------------------------
__global__ __launch_bounds__(256) void out_mfma(const short* __restrict__ A,
                                                const short* __restrict__ Wb,
                                                const float* __restrict__ bias,
                                                float* __restrict__ C) {
    __shared__ __align__(16) short As[64][72];
    __shared__ __align__(16) short Bs[64][72];
    const int m0 = blockIdx.y * 64, n0 = blockIdx.x * 64;
    const int tid = threadIdx.x;
    const int w = tid >> 6, lane = tid & 63;
    const int m = lane & 15, g = lane >> 4;
    const int srow = tid >> 2, scol = (tid & 3) * 16;

    f32x4 acc[4] = {};

    const short* ap = A + (size_t)(m0 + srow) * DIMC + scol;
    const short* bp = Wb + (size_t)(n0 + srow) * DIMC + scol;

    short8 pa[2], pb[2];
#pragma unroll
    for (int i = 0; i < 2; i++) {
        pa[i] = *(const short8*)(ap + i * 8);
        pb[i] = *(const short8*)(bp + i * 8);
    }

    for (int kt = 0; kt < DIMC; kt += 64) {
        __syncthreads();
#pragma unroll
        for (int i = 0; i < 2; i++) {
            *(short8*)&As[srow][scol + i * 8] = pa[i];
            *(short8*)&Bs[srow][scol + i * 8] = pb[i];
        }
        __syncthreads();
        if (kt + 64 < DIMC) {
#pragma unroll
            for (int i = 0; i < 2; i++) {
                pa[i] = *(const short8*)(ap + kt + 64 + i * 8);
                pb[i] = *(const short8*)(bp + kt + 64 + i * 8);
            }
        }
#pragma unroll
        for (int kk = 0; kk < 2; kk++) {
            short8 af = *(const short8*)&As[w * 16 + m][kk * 32 + g * 8];
#pragma unroll
            for (int nt = 0; nt < 4; nt++) {
                short8 bf = *(const short8*)&Bs[nt * 16 + m][kk * 32 + g * 8];
                acc[nt] = __builtin_amdgcn_mfma_f32_16x16x32_bf16(af, bf, acc[nt], 0, 0, 0);
            }
        }
    }

    float bv[4];
#pragma unroll
    for (int nt = 0; nt < 4; nt++) bv[nt] = bias[n0 + nt * 16 + m];
#pragma unroll
    for (int nt = 0; nt < 4; nt++)
#pragma unroll
        for (int r = 0; r < 4; r++)
            C[(size_t)(m0 + w * 16 + g * 4 + r) * DIMC + n0 + nt * 16 + m] = acc[nt][r] + bv[nt];
}

extern "C" void kernel_launch(void* const* d_in, const int* in_sizes, int n_in,
                              void* d_out, int out_size, void* d_ws, size_t ws_size,
                              hipStream_t stream) {
    const float* x     = (const float*)d_in[0];
    const float* w_qkv = (const float*)d_in[1];
    const float* b_qkv = (const float*)d_in[2];
    const float* w_out = (const float*)d_in[3];
    const float* b_out = (const float*)d_in[4];
    float* out = (float*)d_out;

    const size_t HSZ = (size_t)BATCH * NHEADS * SEQ * HDIM;
    short* xb  = (short*)d_ws;
    short* wqb = xb + NX;
    short* wob = wqb + NQW;
    short* qw  = wob + NOW;
    short* kw  = qw + HSZ;
    short* vw  = kw + HSZ;
    short* zb  = vw + HSZ;

    cvt_bf16<<<(NX + NQW + NOW) / 1024, 256, 0, stream>>>(x, w_qkv, w_out, xb, wqb, wob);
    qkv_mfma<<<dim3(12, 64), 256, 0, stream>>>(xb, wqb, b_qkv, qw, kw, vw);
    attn_tile<<<dim3(16, 32), 256, 0, stream>>>(qw, kw, vw, zb);
    out_mfma<<<dim3(4, 128), 256, 0, stream>>>(zb, wob, b_out, out);
}

// Round 14
// 112.840 us; speedup vs baseline: 1.0220x; 1.0220x over previous
//
#include <hip/hip_runtime.h>

// Round 13: attention re-waved. Block 512 thr = 8 waves (2 q-halves x 4
// kv-quarters): per-wave VGPR ~110 (launch_bounds(512,4) caps 128) -> 4
// waves/SIMD, 2x R8's latency hiding, with R8's exact AI / LDS traffic /
// inner body (sigma-perm K, register-local P, ones-MFMA l).
// cvt/qkv/out = R8-passing versions, unchanged. grid(16,32).

#define SEQ 2048
#define BATCH 4
#define NHEADS 8
#define HDIM 32
#define DIMC 256
#define SCALE_LOG2E 0.09016844005556021f  // (1/16)*log2(e)

typedef __attribute__((ext_vector_type(8))) short short8;
typedef __attribute__((ext_vector_type(4))) float f32x4;

union BF8 { unsigned u[4]; short8 s8; };

__device__ __forceinline__ unsigned pk2bf(float a, float b) {
    union { float f; unsigned u; } ua, ub;
    ua.f = a; ub.f = b;
    return __builtin_amdgcn_perm(ub.u + 0x8000u, ua.u + 0x8000u, 0x07060302u);
}
__device__ __forceinline__ short f2bf(float a) {
    union { float f; unsigned u; } x; x.f = a;
    return (short)((x.u + 0x8000u) >> 16);
}

#define NX (BATCH * SEQ * DIMC)
#define NQW (3 * DIMC * DIMC)
#define NOW (DIMC * DIMC)

__global__ __launch_bounds__(256) void cvt_bf16(const float* __restrict__ x,
                                                const float* __restrict__ wq,
                                                const float* __restrict__ wo,
                                                short* __restrict__ xb,
                                                short* __restrict__ wqb,
                                                short* __restrict__ wob) {
    int i = (blockIdx.x * 256 + threadIdx.x) * 4;
    const float* src;
    short* dst;
    int off;
    if (i < NX) { src = x; dst = xb; off = i; }
    else if (i < NX + NQW) { src = wq; dst = wqb; off = i - NX; }
    else { src = wo; dst = wob; off = i - NX - NQW; }
    float4 v = *(const float4*)&src[off];
    uint2 p;
    p.x = pk2bf(v.x, v.y);
    p.y = pk2bf(v.z, v.w);
    *(uint2*)&dst[off] = p;
}

// ---------------------------------------------------------------------------
// QKV GEMM (R8): 128x64 tile, 768 blocks, software-pipelined staging.
// ---------------------------------------------------------------------------
__global__ __launch_bounds__(256) void qkv_mfma(const short* __restrict__ Xb,
                                                const short* __restrict__ Wb,
                                                const float* __restrict__ bias,
                                                short* __restrict__ Q,
                                                short* __restrict__ Kd,
                                                short* __restrict__ V) {
    __shared__ __align__(16) union SM {
        struct { short A[128][72]; short B[64][72]; } ab;
        short CQ[128][72];
        short CV[64][136];
    } sm;

    const int m0 = blockIdx.y * 128, bx = blockIdx.x;
    const int n0 = bx * 64;
    const int tid = threadIdx.x;
    const int w = tid >> 6, lane = tid & 63;
    const int m = lane & 15, g = lane >> 4;
    const int wr = w >> 1, wc = w & 1;

    const int arow = tid >> 1, acol = (tid & 1) * 32;
    const int brow = tid >> 2, bcol = (tid & 3) * 16;

    f32x4 acc[4][2] = {};

    const short* ap = Xb + (size_t)(m0 + arow) * DIMC + acol;
    const short* bp = Wb + (size_t)(n0 + brow) * DIMC + bcol;

    short8 pa[4], pb[2];
#pragma unroll
    for (int i = 0; i < 4; i++) pa[i] = *(const short8*)(ap + i * 8);
#pragma unroll
    for (int i = 0; i < 2; i++) pb[i] = *(const short8*)(bp + i * 8);

    for (int kt = 0; kt < DIMC; kt += 64) {
        __syncthreads();
#pragma unroll
        for (int i = 0; i < 4; i++) *(short8*)&sm.ab.A[arow][acol + i * 8] = pa[i];
#pragma unroll
        for (int i = 0; i < 2; i++) *(short8*)&sm.ab.B[brow][bcol + i * 8] = pb[i];
        __syncthreads();
        if (kt + 64 < DIMC) {
#pragma unroll
            for (int i = 0; i < 4; i++) pa[i] = *(const short8*)(ap + kt + 64 + i * 8);
#pragma unroll
            for (int i = 0; i < 2; i++) pb[i] = *(const short8*)(bp + kt + 64 + i * 8);
        }
#pragma unroll
        for (int kk = 0; kk < 2; kk++) {
            short8 af[4], bf[2];
#pragma unroll
            for (int mt = 0; mt < 4; mt++)
                af[mt] = *(const short8*)&sm.ab.A[wr * 64 + mt * 16 + m][kk * 32 + g * 8];
#pragma unroll
            for (int nt = 0; nt < 2; nt++)
                bf[nt] = *(const short8*)&sm.ab.B[wc * 32 + nt * 16 + m][kk * 32 + g * 8];
#pragma unroll
            for (int mt = 0; mt < 4; mt++)
#pragma unroll
                for (int nt = 0; nt < 2; nt++)
                    acc[mt][nt] = __builtin_amdgcn_mfma_f32_16x16x32_bf16(af[mt], bf[nt], acc[mt][nt], 0, 0, 0);
        }
    }

    const int which = bx >> 2;
    const int h0 = (bx & 3) * 2;
    const int bidx = blockIdx.y >> 4;
    const int ntok0 = (blockIdx.y & 15) * 128;
    float bv[2];
#pragma unroll
    for (int nt = 0; nt < 2; nt++) bv[nt] = bias[n0 + wc * 32 + nt * 16 + m];

    __syncthreads();
    if (which != 2) {
        const float qs = (which == 0) ? SCALE_LOG2E : 1.0f;
#pragma unroll
        for (int mt = 0; mt < 4; mt++)
#pragma unroll
            for (int nt = 0; nt < 2; nt++)
#pragma unroll
                for (int r = 0; r < 4; r++)
                    sm.CQ[wr * 64 + mt * 16 + g * 4 + r][wc * 32 + nt * 16 + m] =
                        f2bf((acc[mt][nt][r] + bv[nt]) * qs);
        __syncthreads();
        short* dst = (which == 0) ? Q : Kd;
        const int tok = tid >> 1, d0 = (tid & 1) * 16;
#pragma unroll
        for (int hh = 0; hh < 2; hh++) {
            size_t o = ((size_t)((bidx * NHEADS + h0 + hh) * SEQ) + ntok0 + tok) * HDIM + d0;
            *(short8*)&dst[o] = *(const short8*)&sm.CQ[tok][hh * 32 + d0];
            *(short8*)&dst[o + 8] = *(const short8*)&sm.CQ[tok][hh * 32 + d0 + 8];
        }
    } else {
#pragma unroll
        for (int mt = 0; mt < 4; mt++)
#pragma unroll
            for (int nt = 0; nt < 2; nt++) {
                uint2 p;
                p.x = pk2bf(acc[mt][nt][0] + bv[nt], acc[mt][nt][1] + bv[nt]);
                p.y = pk2bf(acc[mt][nt][2] + bv[nt], acc[mt][nt][3] + bv[nt]);
                *(uint2*)&sm.CV[wc * 32 + nt * 16 + m][wr * 64 + mt * 16 + g * 4] = p;
            }
        __syncthreads();
        const int col = tid >> 2, t0 = (tid & 3) * 32;
        const int hh = col >> 5, d = col & 31;
        size_t o = ((size_t)((bidx * NHEADS + h0 + hh) * HDIM) + d) * SEQ + ntok0 + t0;
#pragma unroll
        for (int c2 = 0; c2 < 4; c2++)
            *(short8*)&V[o + c2 * 8] = *(const short8*)&sm.CV[col][t0 + c2 * 8];
    }
}

// ---------------------------------------------------------------------------
// Attention: 512 threads = 8 waves (qh in {0,1} x ks in {0..3}).
// Block tile 128 q x 128 kv (16 iters, double-buffered LDS = R8 staging).
// Wave (qh,ks): q rows qh*64..+64 (4 frags), kv ks*32..+32 (R8 inner body).
// sigma-permuted K staging; register-local P; ones-MFMA l.
// Single-phase cross-ks epilogue. grid(16,32)=512 blocks, 2/CU.
// ---------------------------------------------------------------------------
__global__ __launch_bounds__(512, 4) void attn_tile(const short* __restrict__ Q,
                                                    const short* __restrict__ K,
                                                    const short* __restrict__ V,  // [bh][d][tok]
                                                    short* __restrict__ Zb) {
    __shared__ __align__(16) union SM {
        struct { short Ks[2][128][40]; short Vs[2][32][136]; } kv;   // 37888 B
        struct { float O[4][128][36]; float L[4][128]; } ep;         // 75776 B
    } sm;

    const int bh = blockIdx.y;
    const int b = bh >> 3, h = bh & 7;
    const int q0 = blockIdx.x * 128;
    const short* qb = Q + (size_t)bh * SEQ * HDIM;
    const short* kb = K + (size_t)bh * SEQ * HDIM;
    const short* vb = V + (size_t)bh * HDIM * SEQ;
    const int tid = threadIdx.x;                 // 0..511
    const int w = tid >> 6, lane = tid & 63;
    const int m = lane & 15, g = lane >> 4;
    const int ks = w & 3, qh = w >> 2;

    short8 qfr[4];
#pragma unroll
    for (int qt = 0; qt < 4; qt++)
        qfr[qt] = *(const short8*)(qb + (size_t)(q0 + qh * 64 + qt * 16 + m) * HDIM + g * 8);

    // staging: 1 K-load + 1 V-load per thread (512 thr cover 128x32 + 32x128)
    const int krow = tid >> 2, kcol = (tid & 3) * 8;
    const int rl = krow & 31;
    const int lrow = (krow & ~31) | (((rl >> 2) & 1) << 4) | ((rl >> 3) << 2) | (rl & 3);
    const int vrow = tid >> 4, vcol = (tid & 15) * 8;

    f32x4 o[4][2] = {};
    f32x4 ol[4] = {};
    const short8 ones = {0x3F80, 0x3F80, 0x3F80, 0x3F80, 0x3F80, 0x3F80, 0x3F80, 0x3F80};

    short8 k0 = *(const short8*)(kb + (size_t)krow * HDIM + kcol);
    short8 v0 = *(const short8*)(vb + (size_t)vrow * SEQ + vcol);
    *(short8*)&sm.kv.Ks[0][lrow][kcol] = k0;
    *(short8*)&sm.kv.Vs[0][vrow][vcol] = v0;
    __syncthreads();

    for (int it = 0; it < SEQ / 128; ++it) {
        const int buf = it & 1;
        if (it < SEQ / 128 - 1) {
            const int kn = (it + 1) * 128;
            k0 = *(const short8*)(kb + (size_t)(kn + krow) * HDIM + kcol);
            v0 = *(const short8*)(vb + (size_t)vrow * SEQ + kn + vcol);
        }

        short8 kf0 = *(const short8*)&sm.kv.Ks[buf][ks * 32 + m][g * 8];
        short8 kf1 = *(const short8*)&sm.kv.Ks[buf][ks * 32 + 16 + m][g * 8];
        short8 vf0 = *(const short8*)&sm.kv.Vs[buf][m][ks * 32 + g * 8];
        short8 vf1 = *(const short8*)&sm.kv.Vs[buf][16 + m][ks * 32 + g * 8];

#pragma unroll
        for (int qt = 0; qt < 4; qt++) {
            f32x4 z4 = {0.f, 0.f, 0.f, 0.f};
            f32x4 st0 = __builtin_amdgcn_mfma_f32_16x16x32_bf16(kf0, qfr[qt], z4, 0, 0, 0);
            f32x4 st1 = __builtin_amdgcn_mfma_f32_16x16x32_bf16(kf1, qfr[qt], z4, 0, 0, 0);
            BF8 a;
            a.u[0] = pk2bf(__builtin_amdgcn_exp2f(st0[0]), __builtin_amdgcn_exp2f(st0[1]));
            a.u[1] = pk2bf(__builtin_amdgcn_exp2f(st0[2]), __builtin_amdgcn_exp2f(st0[3]));
            a.u[2] = pk2bf(__builtin_amdgcn_exp2f(st1[0]), __builtin_amdgcn_exp2f(st1[1]));
            a.u[3] = pk2bf(__builtin_amdgcn_exp2f(st1[2]), __builtin_amdgcn_exp2f(st1[3]));
            o[qt][0] = __builtin_amdgcn_mfma_f32_16x16x32_bf16(a.s8, vf0, o[qt][0], 0, 0, 0);
            o[qt][1] = __builtin_amdgcn_mfma_f32_16x16x32_bf16(a.s8, vf1, o[qt][1], 0, 0, 0);
            ol[qt] = __builtin_amdgcn_mfma_f32_16x16x32_bf16(a.s8, ones, ol[qt], 0, 0, 0);
        }

        if (it < SEQ / 128 - 1) {
            const int nb = buf ^ 1;
            *(short8*)&sm.kv.Ks[nb][lrow][kcol] = k0;
            *(short8*)&sm.kv.Vs[nb][vrow][vcol] = v0;
        }
        __syncthreads();
    }

    // Single-phase cross-ks reduction epilogue (LDS union reuse).
#pragma unroll
    for (int qt = 0; qt < 4; qt++) {
        const int row = qh * 64 + qt * 16 + g * 4;
#pragma unroll
        for (int dh = 0; dh < 2; dh++)
#pragma unroll
            for (int r = 0; r < 4; r++)
                sm.ep.O[ks][row + r][dh * 16 + m] = o[qt][dh][r];
        if (m == 0)
#pragma unroll
            for (int r = 0; r < 4; r++)
                sm.ep.L[ks][row + r] = ol[qt][r];
    }
    __syncthreads();

    const int ql = tid >> 2, d0 = (tid & 3) * 8;   // 128 rows x 32 cols
    float lt = sm.ep.L[0][ql] + sm.ep.L[1][ql] + sm.ep.L[2][ql] + sm.ep.L[3][ql];
    float inv = __builtin_amdgcn_rcpf(lt);
    float sv[8];
#pragma unroll
    for (int j = 0; j < 8; j++)
        sv[j] = sm.ep.O[0][ql][d0 + j] + sm.ep.O[1][ql][d0 + j] +
                sm.ep.O[2][ql][d0 + j] + sm.ep.O[3][ql][d0 + j];
    BF8 pz;
#pragma unroll
    for (int j = 0; j < 4; j++)
        pz.u[j] = pk2bf(sv[2 * j] * inv, sv[2 * j + 1] * inv);
    *(short8*)&Zb[(size_t)(b * SEQ + q0 + ql) * DIMC + h * HDIM + d0] = pz.s8;
}

// ---------------------------------------------------------------------------
// Out GEMM (R8): 64x64 tile, 512 blocks, software-pipelined staging.
// ---------------------------------------------------------------------------
__global__ __launch_bounds__(256) void out_mfma(const short* __restrict__ A,
                                                const short* __restrict__ Wb,
                                                const float* __restrict__ bias,
                                                float* __restrict__ C) {
    __shared__ __align__(16) short As[64][72];
    __shared__ __align__(16) short Bs[64][72];
    const int m0 = blockIdx.y * 64, n0 = blockIdx.x * 64;
    const int tid = threadIdx.x;
    const int w = tid >> 6, lane = tid & 63;
    const int m = lane & 15, g = lane >> 4;
    const int srow = tid >> 2, scol = (tid & 3) * 16;

    f32x4 acc[4] = {};

    const short* ap = A + (size_t)(m0 + srow) * DIMC + scol;
    const short* bp = Wb + (size_t)(n0 + srow) * DIMC + scol;

    short8 pa[2], pb[2];
#pragma unroll
    for (int i = 0; i < 2; i++) {
        pa[i] = *(const short8*)(ap + i * 8);
        pb[i] = *(const short8*)(bp + i * 8);
    }

    for (int kt = 0; kt < DIMC; kt += 64) {
        __syncthreads();
#pragma unroll
        for (int i = 0; i < 2; i++) {
            *(short8*)&As[srow][scol + i * 8] = pa[i];
            *(short8*)&Bs[srow][scol + i * 8] = pb[i];
        }
        __syncthreads();
        if (kt + 64 < DIMC) {
#pragma unroll
            for (int i = 0; i < 2; i++) {
                pa[i] = *(const short8*)(ap + kt + 64 + i * 8);
                pb[i] = *(const short8*)(bp + kt + 64 + i * 8);
            }
        }
#pragma unroll
        for (int kk = 0; kk < 2; kk++) {
            short8 af = *(const short8*)&As[w * 16 + m][kk * 32 + g * 8];
#pragma unroll
            for (int nt = 0; nt < 4; nt++) {
                short8 bf = *(const short8*)&Bs[nt * 16 + m][kk * 32 + g * 8];
                acc[nt] = __builtin_amdgcn_mfma_f32_16x16x32_bf16(af, bf, acc[nt], 0, 0, 0);
            }
        }
    }

    float bv[4];
#pragma unroll
    for (int nt = 0; nt < 4; nt++) bv[nt] = bias[n0 + nt * 16 + m];
#pragma unroll
    for (int nt = 0; nt < 4; nt++)
#pragma unroll
        for (int r = 0; r < 4; r++)
            C[(size_t)(m0 + w * 16 + g * 4 + r) * DIMC + n0 + nt * 16 + m] = acc[nt][r] + bv[nt];
}

extern "C" void kernel_launch(void* const* d_in, const int* in_sizes, int n_in,
                              void* d_out, int out_size, void* d_ws, size_t ws_size,
                              hipStream_t stream) {
    const float* x     = (const float*)d_in[0];
    const float* w_qkv = (const float*)d_in[1];
    const float* b_qkv = (const float*)d_in[2];
    const float* w_out = (const float*)d_in[3];
    const float* b_out = (const float*)d_in[4];
    float* out = (float*)d_out;

    const size_t HSZ = (size_t)BATCH * NHEADS * SEQ * HDIM;
    short* xb  = (short*)d_ws;
    short* wqb = xb + NX;
    short* wob = wqb + NQW;
    short* qw  = wob + NOW;
    short* kw  = qw + HSZ;
    short* vw  = kw + HSZ;
    short* zb  = vw + HSZ;

    cvt_bf16<<<(NX + NQW + NOW) / 1024, 256, 0, stream>>>(x, w_qkv, w_out, xb, wqb, wob);
    qkv_mfma<<<dim3(12, 64), 256, 0, stream>>>(xb, wqb, b_qkv, qw, kw, vw);
    attn_tile<<<dim3(16, 32), 512, 0, stream>>>(qw, kw, vw, zb);
    out_mfma<<<dim3(4, 128), 256, 0, stream>>>(zb, wob, b_out, out);
}